// Round 12
// baseline (120.684 us; speedup 1.0000x reference)
//
#include <hip/hip_runtime.h>

#define BIG 1e8f
#define LN2 0.69314718f
#define LOG2E 1.44269504f
#define M2L -2.8853900818f  /* -2*log2(e) */

#define RSLOT 112           /* band ring slots (anti-diagonal rows); 8-divisible */
#define DRB 1040            /* drow stride bytes: 256 cols * 4B(half2) + 16 pad */

/* dynamic LDS layout */
#define OFF_XH   116480     /* band: [0, 116480) = 112*1040 */
#define OFF_X2S  132864     /* xh: 16384 B f16 */
#define OFF_Y2S  133888
#define OFF_RDY  134912     /* 16 ready flags */
#define OFF_PRG  134976     /* consumer progress */
#define LDS_BYTES 135040

typedef _Float16 half8 __attribute__((ext_vector_type(8)));
typedef _Float16 half2_t __attribute__((ext_vector_type(2)));
typedef float f32x4 __attribute__((ext_vector_type(4)));

__device__ __forceinline__ float exp2g(float x) {
#if __has_builtin(__builtin_amdgcn_exp2f)
    return __builtin_amdgcn_exp2f(x);
#else
    return exp2f(x);
#endif
}
__device__ __forceinline__ float log2g(float x) {
#if __has_builtin(__builtin_amdgcn_logf)
    return __builtin_amdgcn_logf(x);
#else
    return log2f(x);
#endif
}

__device__ __forceinline__ half2_t pkrtz(float a, float b) {
    return __builtin_bit_cast(half2_t, __builtin_amdgcn_cvt_pkrtz(a, b));
}

// whole-wave shift-up-by-1 via DPP wave_shr:1; lane 0 receives oldv.
__device__ __forceinline__ float shfl_up1(float v, float oldv) {
    int r = __builtin_amdgcn_update_dpp(
        __builtin_bit_cast(int, oldv), __builtin_bit_cast(int, v),
        0x138 /*wave_shr:1*/, 0xf, 0xf, false);
    return __builtin_bit_cast(float, r);
}

__device__ __forceinline__ void dec2(unsigned int w, float& a, float& b) {
    half2_t h = __builtin_bit_cast(half2_t, w);
    a = (float)h[0];
    b = (float)h[1];
}

// Mask words: per-column-DISTINCT huge f16 values. Band ring PREFILLED with
// this pattern in phase 0 (gen-1 reads decode to exactly the old masked
// values); post-window stale reads provably never reach an active lane.
#define MASKW0 0x7BFF7BFFu  /* 65504 */
#define MASKW1 0x70007000u  /* 8192  */
#define MASKW2 0x60006000u  /* 512   */
#define MASKW3 0x50005000u  /* 32    */

// One block = one batch, 2 waves on 2 SIMDs.
// Wave 1 (producer): MFMA dist staging into anti-diagonal LDS ring. Proven.
// Wave 0 (consumer): DP wavefront in exponential-pair form (v = M - log2(S)),
//   PHASE-SPLIT superstep for in-order-issue trans-latency hiding:
//     M-phase A (min3/add spine + deltas) -> 12 exp2 issues ->
//     M-phase B -> 12 exp2 issues -> decode(next drow) ->
//     S-phase A -> S-phase B -> commit.
//   Arithmetic identical to the cell3 form (same fma structure), reordered.
__global__ __launch_bounds__(128, 1) void sdtw_kernel(
    const float* __restrict__ x, const float* __restrict__ y,
    float* __restrict__ out) {
    extern __shared__ __align__(16) char smem[];
    unsigned char* band = (unsigned char*)smem;
    _Float16* xh = (_Float16*)(smem + OFF_XH);
    float* x2sL = (float*)(smem + OFF_X2S);   // row norms * log2(e)
    float* y2sL = (float*)(smem + OFF_Y2S);
    volatile int* rdy = (volatile int*)(smem + OFF_RDY);
    volatile int* prg = (volatile int*)(smem + OFF_PRG);

    const int tid = threadIdx.x;  // 0..127
    const int b = blockIdx.x;
    const float* xb = x + (size_t)b * 8192;
    const float* yb = y + (size_t)b * 8192;

    // ---- phase 0 (both waves): mask-prefill band; stage x; norms; flags ----
    {
        const uint4 mw = {MASKW0, MASKW1, MASKW2, MASKW3};
        uint4* bp = (uint4*)smem;
        for (int i = tid; i < (OFF_XH / 16); i += 128) bp[i] = mw;
    }
#pragma unroll
    for (int rr = 0; rr < 2; rr++) {
        const int r = tid + rr * 128;
        const float4* px = (const float4*)(xb + r * 32);
        union { _Float16 h[32]; half8 v[4]; } uc;
        float s2 = 0.f;
#pragma unroll
        for (int q = 0; q < 8; q++) {
            float4 f = px[q];
            s2 += f.x * f.x + f.y * f.y + f.z * f.z + f.w * f.w;
            uc.h[4 * q + 0] = (_Float16)f.x;
            uc.h[4 * q + 1] = (_Float16)f.y;
            uc.h[4 * q + 2] = (_Float16)f.z;
            uc.h[4 * q + 3] = (_Float16)f.w;
        }
        half8* dst = (half8*)&xh[r * 32];
#pragma unroll
        for (int q = 0; q < 4; q++) dst[q] = uc.v[q];
        x2sL[r] = s2 * LOG2E;

        const float4* py = (const float4*)(yb + r * 32);
        float t2 = 0.f;
#pragma unroll
        for (int q = 0; q < 8; q++) {
            float4 f = py[q];
            t2 += f.x * f.x + f.y * f.y + f.z * f.z + f.w * f.w;
        }
        y2sL[r] = t2 * LOG2E;
    }
    if (tid < 16) rdy[tid] = 0;
    if (tid == 16) *prg = 0;
    __syncthreads();

    if (tid >= 64) {
        // ================= producer wave =================
        const int lane = tid - 64;
        const int qd = lane >> 4, xr = lane & 15;

        half8 yfrag[16];  // B-frags: lane holds y[ci*16+xr][qd*8+j]
        float yvL[16];
#pragma unroll
        for (int ci = 0; ci < 16; ci++) {
            const float* yp = yb + (ci * 16 + xr) * 32 + qd * 8;
            float4 f0 = *(const float4*)yp;
            float4 f1 = *(const float4*)(yp + 4);
            half8 v;
            v[0] = (_Float16)f0.x; v[1] = (_Float16)f0.y;
            v[2] = (_Float16)f0.z; v[3] = (_Float16)f0.w;
            v[4] = (_Float16)f1.x; v[5] = (_Float16)f1.y;
            v[6] = (_Float16)f1.z; v[7] = (_Float16)f1.w;
            yfrag[ci] = v;
            yvL[ci] = y2sL[ci * 16 + xr];
        }

        for (int sg = 0; sg < 16; sg++) {
            // ring-reuse gate: stripe sg touches drows [8sg, 8sg+70]; the
            // aliased drows (d-112) need consumer progress >= 8sg-40.
            if (sg >= 6) {
                const int need = 8 * sg - 40;
                while (*prg < need) {}
            }
            const half8 xf = *(const half8*)&xh[(sg * 16 + xr) * 32 + qd * 8];
            const float4 xl = *(const float4*)&x2sL[sg * 16 + qd * 4];
            const int p0 = 8 * sg + 2 * qd;  // global pair of acc[0],acc[1]
#pragma unroll
            for (int ci = 0; ci < 16; ci++) {
                f32x4 acc = {0.f, 0.f, 0.f, 0.f};
                acc = __builtin_amdgcn_mfma_f32_16x16x32_f16(xf, yfrag[ci], acc, 0, 0, 0);
                const int c = ci * 16 + xr;
                const float yv = yvL[ci];
                const float d0 = fmaxf(fmaf(M2L, acc[0], xl.x + yv), 0.f);
                const float d1 = fmaxf(fmaf(M2L, acc[1], xl.y + yv), 0.f);
                const float d2 = fmaxf(fmaf(M2L, acc[2], xl.z + yv), 0.f);
                const float d3 = fmaxf(fmaf(M2L, acc[3], xl.w + yv), 0.f);
                const half2_t h01 = pkrtz(d0, d1);
                const half2_t h23 = pkrtz(d2, d3);
                const int dr0 = p0 + (c >> 2);          // anti-diagonal row
                int s0_ = dr0;     if (s0_ >= RSLOT) s0_ -= RSLOT;
                int s1_ = dr0 + 1; if (s1_ >= RSLOT) s1_ -= RSLOT;
                *(half2_t*)&band[s0_ * DRB + 4 * c] = h01;
                *(half2_t*)&band[s1_ * DRB + 4 * c] = h23;
            }
            __threadfence_block();  // drain LDS writes before flagging
            if (lane == 0) rdy[sg] = 1;
        }
        return;
    }

    // ================= consumer (DP) wave =================
    const int lane = tid;
    // previous-B-row pairs + prev diag-relay pair G0 (all in pair form)
    float pBM[4], pBS[4];
    pBM[0] = BIG; pBS[0] = 1.f;
    pBM[1] = BIG; pBS[1] = 1.f;
    pBM[2] = BIG; pBS[2] = 1.f;
    pBM[3] = BIG; pBS[3] = 1.f;
    float G0M = (lane == 0) ? 0.f : BIG, G0S = 1.f;
    float MpA3 = BIG, SpA3 = 1.f, MpB3 = BIG, SpB3 = 1.f;

    float dAc[4], dBc[4];  // current decoded inputs

    auto decode = [&](uint4 w) {
        dec2(w.x, dAc[0], dBc[0]);
        dec2(w.y, dAc[1], dBc[1]);
        dec2(w.z, dAc[2], dBc[2]);
        dec2(w.w, dAc[3], dBc[3]);
    };

    while (rdy[0] == 0) {}
    decode(*(const uint4*)&band[16 * lane]);  // drow 0 -> step 1

    // PHASE-SPLIT superstep (arithmetic == cell3 form, reordered so no
    // instruction in program order consumes a trans result issued < ~100cy
    // earlier). A-cell k: up=pB[k], diag=(k?pB[k-1]:G0), left=chain(MLA).
    // B-cell k: up=A[k], diag=(k?A[k-1]:L-relay), left=chain(MLB).
    auto step = [&](const char* gb, int koff) {
        const float MLA = shfl_up1(MpA3, BIG);
        const float MLB = shfl_up1(MpB3, BIG);
        const float SLA = shfl_up1(SpA3, 1.f);
        const float SLB = shfl_up1(SpB3, 1.f);

        const uint4 wnext = *(const uint4*)(gb + koff);

        // ---- M-phase A: fast min3/add spine + exponent args ----
        float MA[4], xuA[4], xgA[4], xlA[4];
        {
            float ml = MLA, gm = G0M;
#pragma unroll
            for (int k = 0; k < 4; k++) {
                const float mu = fminf(fminf(pBM[k], gm), ml);
                xuA[k] = mu - pBM[k];
                xgA[k] = mu - gm;
                xlA[k] = mu - ml;
                MA[k] = dAc[k] + mu;
                ml = MA[k];
                gm = pBM[k];
            }
        }
        // ---- exp issue A (12 independent trans) ----
        float euA[4], egA[4], elA[4];
#pragma unroll
        for (int k = 0; k < 4; k++) {
            euA[k] = exp2g(xuA[k]);
            egA[k] = exp2g(xgA[k]);
            elA[k] = exp2g(xlA[k]);
        }
        // ---- M-phase B ----
        float MB[4], xuB[4], xgB[4], xlB[4];
        {
            float ml = MLB, gm = MLA;
#pragma unroll
            for (int k = 0; k < 4; k++) {
                const float mu = fminf(fminf(MA[k], gm), ml);
                xuB[k] = mu - MA[k];
                xgB[k] = mu - gm;
                xlB[k] = mu - ml;
                MB[k] = dBc[k] + mu;
                ml = MB[k];
                gm = MA[k];
            }
        }
        // ---- exp issue B (12 independent trans) ----
        float euB[4], egB[4], elB[4];
#pragma unroll
        for (int k = 0; k < 4; k++) {
            euB[k] = exp2g(xuB[k]);
            egB[k] = exp2g(xgB[k]);
            elB[k] = exp2g(xlB[k]);
        }

        // ---- decode next step's inputs (spacer; dAc/dBc already consumed) ----
        decode(wnext);

        // ---- S-phase A (exps A issued ~150cy ago: ready) ----
        float SA[4];
        {
            float sl = SLA, sg = G0S;
#pragma unroll
            for (int k = 0; k < 4; k++) {
                const float pre = fmaf(pBS[k], euA[k], sg * egA[k]);
                SA[k] = fmaf(sl, elA[k], pre);
                sl = SA[k];
                sg = pBS[k];
            }
        }
        // ---- S-phase B ----
        float SB[4];
        {
            float sl = SLB, sg = SLA;
#pragma unroll
            for (int k = 0; k < 4; k++) {
                const float pre = fmaf(SA[k], euB[k], sg * egB[k]);
                SB[k] = fmaf(sl, elB[k], pre);
                sl = SB[k];
                sg = SA[k];
            }
        }

        // commit
        MpA3 = MA[3]; SpA3 = SA[3];
        MpB3 = MB[3]; SpB3 = SB[3];
#pragma unroll
        for (int k = 0; k < 4; k++) { pBM[k] = MB[k]; pBS[k] = SB[k]; }
        G0M = MLB; G0S = SLB;
    };

    // prologue: supersteps 1..7 (stripe 0 covers drows 0..7)
    {
        const char* gb0 = (const char*)&band[16 * lane];
#pragma unroll
        for (int s_ = 1; s_ < 8; s_++) step(gb0, s_ * DRB);
    }

    // 23 groups of 8 supersteps; poll/publish at group head; group-shared
    // fetch base (RSLOT=112 is 8-divisible -> no wrap within a group).
    for (int g = 1; g < 24; g++) {
        int st = (g > 15) ? 15 : g;
        while (rdy[st] == 0) {}
        if (lane == 0) *prg = 8 * g;
        const int s0 = 8 * g;
        const int slot0 = (s0 >= RSLOT) ? s0 - RSLOT : s0;  // s0 <= 184 < 224
        const char* gb = (const char*)&band[slot0 * DRB + 16 * lane];
        if (g < 23) {
#pragma unroll
            for (int k = 0; k < 8; k++) step(gb, k * DRB);
        } else {
            // g==23: steps 184..191; k==7 fetch (for step 192) is unused --
            // clamp its offset to drow 190's slot at compile time.
#pragma unroll
            for (int k = 0; k < 8; k++) step(gb, (k == 7 ? 6 : k) * DRB);
        }
    }

    // lane 63's superstep-191 commit is the final cell D[256][256]
    if (lane == 63)
        atomicAdd(out, (MpB3 - log2g(SpB3)) * (LN2 / 256.f));
}

extern "C" void kernel_launch(void* const* d_in, const int* in_sizes, int n_in,
                              void* d_out, int out_size, void* d_ws, size_t ws_size,
                              hipStream_t stream) {
    const float* x = (const float*)d_in[0];
    const float* y = (const float*)d_in[1];
    float* out = (float*)d_out;
    const int B = in_sizes[0] / (256 * 32);  // 256

    (void)hipFuncSetAttribute((const void*)sdtw_kernel,
                              hipFuncAttributeMaxDynamicSharedMemorySize,
                              LDS_BYTES);
    (void)hipMemsetAsync(d_out, 0, sizeof(float), stream);
    sdtw_kernel<<<dim3(B), dim3(128), LDS_BYTES, stream>>>(x, y, out);
}